// Round 14
// baseline (68.367 us; speedup 1.0000x reference)
//
#include <hip/hip_runtime.h>

// Analytic collapse (verified R1-R12, absmax 9.8e-4):
//   <Z_0> = c1*...*c7,  <Z_j> = c0*...*cj,  c_j = cos(t_j + theta_j)
// R13 = R12's MFMA structure minus the W-LDS staging: B-fragments are built
// per job from 4 global float4 loads (L2-hot, all blocks share 64 KB of W)
// + in-register truncation-split (hi = high 16 bits, lo = bf16(exact
// residual) -> 2^-17 rel, same class as R12's verified split).
// Block = 16 tokens, 256 thr (4 waves); 512 blocks; ~22 KB LDS -> multiple
// blocks/CU (cross-block phase overlap R12's 1-block/CU couldn't do).
//  P1: 12 (mat,ntile) jobs, 3/wave; A-frags (x, split-bf16 in LDS) loaded
//      once per wave, reused across jobs; 6 MFMA/job; cos+DPP-scan epilogue.
//  P2: all 4 waves, 4 tokens each (R11's gated row-per-lane attention).
//  P3: 4 jobs, 1/wave; scr A-frags from LDS, Wo B-frags from global; 6 MFMA.

typedef float  f32x4  __attribute__((ext_vector_type(4)));
typedef short  bf16x8 __attribute__((ext_vector_type(8)));
typedef unsigned short u16;
typedef unsigned int   u32;

#define WRS 72   // shorts per staged row (64 data + 8 pad) = 144 B
#define SPS 68   // sP row stride (dwords), 16B-aligned

// d *= dpp_row_shr<sh>(d) gated to lanes with (lane&7) >= sh
#define DPP_SHR_STEP(d, j, sh)                                                 \
    {                                                                          \
        float _t = __int_as_float(__builtin_amdgcn_update_dpp(                 \
            0x3f800000, __float_as_int(d), 0x110 + sh, 0xf, 0xf, false));      \
        d *= ((j) >= (sh)) ? _t : 1.0f;                                        \
    }

__device__ __forceinline__ u32 bfh(float f) {          // RTNE bf16 (raw u16)
    const u32 u = __float_as_uint(f);
    return (u + 0x7FFFu + ((u >> 16) & 1u)) >> 16;
}
// trunc-hi split of a pair, packed: hi error captured EXACTLY in residual,
// residual rounded RTNE -> overall 2^-17 rel (R12-verified accuracy class)
__device__ __forceinline__ void bfsplit2(float a, float b, u32& h, u32& l) {
    const u32 ua = __float_as_uint(a), ub = __float_as_uint(b);
    h = (ua >> 16) | (ub & 0xFFFF0000u);
    const float ra = a - __uint_as_float(ua & 0xFFFF0000u);   // exact
    const float rb = b - __uint_as_float(ub & 0xFFFF0000u);   // exact
    l = bfh(ra) | (bfh(rb) << 16);
}
__device__ __forceinline__ bf16x8 mk8(u32 a, u32 b, u32 c, u32 d) {
    uint4 t = make_uint4(a, b, c, d);
    return *(bf16x8*)&t;
}
// build one k-half B-fragment (8 k's) from two global float4's
__device__ __forceinline__ void splitpack(const float4 w0, const float4 w1,
                                          bf16x8& hi, bf16x8& lo) {
    u32 h0, l0, h1, l1, h2, l2, h3, l3;
    bfsplit2(w0.x, w0.y, h0, l0);
    bfsplit2(w0.z, w0.w, h1, l1);
    bfsplit2(w1.x, w1.y, h2, l2);
    bfsplit2(w1.z, w1.w, h3, l3);
    hi = mk8(h0, h1, h2, h3);
    lo = mk8(l0, l1, l2, l3);
}

#define MFMA3(acc, ah, al, bh, bl)                                             \
    acc = __builtin_amdgcn_mfma_f32_16x16x32_bf16(al, bh, acc, 0, 0, 0);       \
    acc = __builtin_amdgcn_mfma_f32_16x16x32_bf16(ah, bl, acc, 0, 0, 0);       \
    acc = __builtin_amdgcn_mfma_f32_16x16x32_bf16(ah, bh, acc, 0, 0, 0);

__global__ __launch_bounds__(256, 4)
void qattn_fused(const float* __restrict__ xg,
                 const float* __restrict__ wqg, const float* __restrict__ wkg,
                 const float* __restrict__ wvg, const float* __restrict__ wog,
                 const float* __restrict__ thg,
                 float* __restrict__ outg)
{
    __shared__ u16 sXh[16 * WRS];                  // 2.3 KB  x hi (split bf16)
    __shared__ u16 sXl[16 * WRS];                  // 2.3 KB  x lo
    __shared__ __align__(16) float sP[48 * SPS];   // 13 KB   z values [m*16+t][e]
    __shared__ u16 sSh[16 * WRS];                  // 2.3 KB  scr hi [rho][col]
    __shared__ u16 sSl[16 * WRS];                  // 2.3 KB  scr lo

    const int tid  = threadIdx.x;
    const int lane = tid & 63;
    const int wg   = tid >> 6;         // 0..3
    const int l15  = lane & 15;
    const int quad = lane >> 4;
    const int j    = lane & 7;
    const int b    = blockIdx.x >> 5;
    const int grp  = blockIdx.x & 31;  // 16-token group in batch row

    // ---- stage x (16 tokens) as split bf16: one float4 per thread ----
    {
        const float4 v = ((const float4*)(xg + (size_t)(b * 512 + grp * 16) * 64))[tid];
        u32 h01, l01, h23, l23;
        bfsplit2(v.x, v.y, h01, l01);
        bfsplit2(v.z, v.w, h23, l23);
        const int o = (tid >> 4) * WRS + 4 * (tid & 15);
        *(uint2*)&sXh[o] = make_uint2(h01, h23);
        *(uint2*)&sXl[o] = make_uint2(l01, l23);
    }
    const float thf = thg[j];
    __syncthreads();                                 // B1: x staged

    // ---- P1: projections via MFMA; 3 (m,nt) jobs/wave; A-frags shared ----
    {
        const int arow = l15 * WRS + quad * 8;
        const bf16x8 ah0 = *(const bf16x8*)&sXh[arow];
        const bf16x8 ah1 = *(const bf16x8*)&sXh[arow + 32];
        const bf16x8 al0 = *(const bf16x8*)&sXl[arow];
        const bf16x8 al1 = *(const bf16x8*)&sXl[arow + 32];
        #pragma unroll
        for (int ia = 0; ia < 3; ++ia) {
            const int aid = wg * 3 + ia;             // 0..11
            const int m = aid >> 2, nt = aid & 3;
            const float* wm = (m == 0) ? wqg : (m == 1) ? wkg : wvg;
            const float* wr = wm + (nt * 16 + l15) * 64 + quad * 8;
            bf16x8 bh0, bl0, bh1, bl1;
            {
                const float4 w0 = *(const float4*)wr;
                const float4 w1 = *(const float4*)(wr + 4);
                splitpack(w0, w1, bh0, bl0);         // k = quad*8 ..
            }
            {
                const float4 w0 = *(const float4*)(wr + 32);
                const float4 w1 = *(const float4*)(wr + 36);
                splitpack(w0, w1, bh1, bl1);         // k = 32 + quad*8 ..
            }
            f32x4 acc = {0.f, 0.f, 0.f, 0.f};
            MFMA3(acc, ah0, al0, bh0, bl0)
            MFMA3(acc, ah1, al1, bh1, bl1)
            // epilogue: lane holds q[token][e], e = nt*16+l15; token=quad*4+r
            #pragma unroll
            for (int r = 0; r < 4; ++r) {
                const float c = __cosf(acc[r] + thf);
                float d = c;                         // inclusive scan (c0..cj)
                DPP_SHR_STEP(d, j, 1)
                DPP_SHR_STEP(d, j, 2)
                DPP_SHR_STEP(d, j, 4)
                float ex = (j == 0) ? 1.0f : c;      // scan excluding c0
                DPP_SHR_STEP(ex, j, 1)
                DPP_SHR_STEP(ex, j, 2)
                DPP_SHR_STEP(ex, j, 4)
                const int row  = m * 16 + quad * 4 + r;
                const int base = row * SPS + nt * 16 + l15;
                if (j > 0)  sP[base]     = d;        // z_j = c0..cj
                if (j == 7) sP[base - 7] = ex;       // z_0 = c1..c7 -> slot 0
            }
        }
    }
    __syncthreads();                                 // B2: z ready

    // ---- P2: row-per-lane attention; 4 tokens/wave, dup lanes gated ----
    {
        const int tg = wg * 4 + (lane >> 4);         // block-local token 0..15
        const int i  = j;                            // head (score row)
        const int qb = tg * SPS;
        const int kb = (16 + tg) * SPS;
        const int vb = (32 + tg) * SPS;
        float q[8];
        *(float4*)&q[0] = *(const float4*)&sP[qb + 8 * i];
        *(float4*)&q[4] = *(const float4*)&sP[qb + 8 * i + 4];
        float pr[8];
        float sum = 0.f;
        #pragma unroll
        for (int jj = 0; jj < 8; ++jj) {             // |s| <= 2.83 -> no max-sub
            const float4 k0 = *(const float4*)&sP[kb + 8 * jj];
            const float4 k1 = *(const float4*)&sP[kb + 8 * jj + 4];
            float s = q[0] * k0.x;
            s = fmaf(q[1], k0.y, s); s = fmaf(q[2], k0.z, s);
            s = fmaf(q[3], k0.w, s); s = fmaf(q[4], k1.x, s);
            s = fmaf(q[5], k1.y, s); s = fmaf(q[6], k1.z, s);
            s = fmaf(q[7], k1.w, s);
            pr[jj] = __expf(s * 0.35355339059327373f);
            sum += pr[jj];
        }
        const float rinv = 1.0f / sum;
        float o[8];
        #pragma unroll
        for (int w = 0; w < 8; ++w) o[w] = 0.f;
        #pragma unroll
        for (int jj = 0; jj < 8; ++jj) {
            const float4 v0 = *(const float4*)&sP[vb + 8 * jj];
            const float4 v1 = *(const float4*)&sP[vb + 8 * jj + 4];
            const float a = pr[jj] * rinv;
            o[0] = fmaf(a, v0.x, o[0]); o[1] = fmaf(a, v0.y, o[1]);
            o[2] = fmaf(a, v0.z, o[2]); o[3] = fmaf(a, v0.w, o[3]);
            o[4] = fmaf(a, v1.x, o[4]); o[5] = fmaf(a, v1.y, o[5]);
            o[6] = fmaf(a, v1.z, o[6]); o[7] = fmaf(a, v1.w, o[7]);
        }
        // scrambled row rho = i*2 + (tg>>3); col base 8*(tg&7); split-bf16
        if (!(lane & 8)) {
            u32 hh[4], ll[4];
            #pragma unroll
            for (int c = 0; c < 4; ++c)
                bfsplit2(o[2 * c], o[2 * c + 1], hh[c], ll[c]);
            const int so = (i * 2 + (tg >> 3)) * WRS + 8 * (tg & 7);
            *(uint4*)&sSh[so] = make_uint4(hh[0], hh[1], hh[2], hh[3]);
            *(uint4*)&sSl[so] = make_uint4(ll[0], ll[1], ll[2], ll[3]);
        }
    }
    __syncthreads();                                 // B3: scr ready

    // ---- P3: y = scr @ Wo^T via MFMA; 1 job/wave (nt2 = wg) ----
    {
        const int arow = l15 * WRS + quad * 8;
        const bf16x8 ah0 = *(const bf16x8*)&sSh[arow];
        const bf16x8 ah1 = *(const bf16x8*)&sSh[arow + 32];
        const bf16x8 al0 = *(const bf16x8*)&sSl[arow];
        const bf16x8 al1 = *(const bf16x8*)&sSl[arow + 32];
        const float* wr = wog + (wg * 16 + l15) * 64 + quad * 8;
        bf16x8 bh0, bl0, bh1, bl1;
        {
            const float4 w0 = *(const float4*)wr;
            const float4 w1 = *(const float4*)(wr + 4);
            splitpack(w0, w1, bh0, bl0);
        }
        {
            const float4 w0 = *(const float4*)(wr + 32);
            const float4 w1 = *(const float4*)(wr + 36);
            splitpack(w0, w1, bh1, bl1);
        }
        f32x4 acc = {0.f, 0.f, 0.f, 0.f};
        MFMA3(acc, ah0, al0, bh0, bl0)
        MFMA3(acc, ah1, al1, bh1, bl1)
        // store: lane holds y[rho][e], rho = quad*4+r, e = wg*16+l15
        const int e = wg * 16 + l15;
        #pragma unroll
        for (int r = 0; r < 4; ++r) {
            const int rho = quad * 4 + r;
            const int R   = (rho >> 1) * 64 + grp * 2 + (rho & 1);
            outg[((size_t)(b * 512 + R)) * 64 + e] = acc[r];
        }
    }
}

extern "C" void kernel_launch(void* const* d_in, const int* in_sizes, int n_in,
                              void* d_out, int out_size, void* d_ws, size_t ws_size,
                              hipStream_t stream) {
    const float* x  = (const float*)d_in[0];
    const float* wq = (const float*)d_in[1];
    const float* wk = (const float*)d_in[2];
    const float* wv = (const float*)d_in[3];
    const float* wo = (const float*)d_in[4];
    const float* th = (const float*)d_in[5];
    float* out = (float*)d_out;
    // B=16, S=512: 16 batches x 32 sixteen-token groups = 512 blocks
    qattn_fused<<<dim3(512), dim3(256), 0, stream>>>(x, wq, wk, wv, wo, th, out);
}